// Round 14
// baseline (2319.809 us; speedup 1.0000x reference)
//
#include <hip/hip_runtime.h>
#include <hip/hip_bf16.h>

// ClassAtt fused pipeline. R14 = R13 with ring depth templated:
//   SLOTS=4: R2-exact schedule (128 KiB LDS, 1 block/CU)  -> G2, G5 (256-block grids)
//   SLOTS=2: 64 KiB LDS -> 2 blocks/CU (m114 cross-block LDS/MFMA overlap),
//            stage-at-top + end-of-iter vmcnt(0) drain    -> G1 (3/CU), G4 (2/CU)
// Within-bench A/B: SLOTS=2 dispatches vs SLOTS=4 dispatches.

typedef __bf16 bf16_t;
typedef __bf16 bf16x4 __attribute__((ext_vector_type(4)));
typedef __bf16 bf16x8 __attribute__((ext_vector_type(8)));
typedef float  f32x4  __attribute__((ext_vector_type(4)));

#define AS1(p) (const __attribute__((address_space(1))) void*)(p)
#define AS3(p) (__attribute__((address_space(3))) void*)(p)

// ---------------- f32 -> bf16 conversion (tube) ----------------
__global__ void cvt_f32_bf16_v4(const float* __restrict__ src, bf16_t* __restrict__ dst,
                                int n4src, int n4tot) {
  for (int i = blockIdx.x * blockDim.x + threadIdx.x; i < n4tot; i += gridDim.x * blockDim.x) {
    bf16x4 o;
    if (i < n4src) {
      float4 f = ((const float4*)src)[i];
      o[0] = (bf16_t)f.x; o[1] = (bf16_t)f.y; o[2] = (bf16_t)f.z; o[3] = (bf16_t)f.w;
    } else {
      o[0] = (bf16_t)0.0f; o[1] = (bf16_t)0.0f; o[2] = (bf16_t)0.0f; o[3] = (bf16_t)0.0f;
    }
    *(bf16x4*)(dst + (size_t)i * 4) = o;
  }
}

// ---------------- all weight cvts merged (one launch; verified) ----------
__global__ void cvt_weights(const float* __restrict__ w1, const float* __restrict__ w2,
                            const float* __restrict__ w3, const float* __restrict__ wh,
                            const float* __restrict__ wd1, const float* __restrict__ wd2,
                            bf16_t* __restrict__ w123, bf16_t* __restrict__ whB,
                            bf16_t* __restrict__ wd1B, bf16_t* __restrict__ wd2B) {
  const int stride = gridDim.x * blockDim.x;
  for (int i = blockIdx.x * blockDim.x + threadIdx.x; i < 2752512; i += stride) {
    const float* s; bf16_t* d; int o; int ns = 1 << 30;
    if (i < 131072)       { s = w1;  d = w123;           o = i; }
    else if (i < 262144)  { s = w2;  d = w123 + 524288;  o = i - 131072; }
    else if (i < 393216)  { s = w3;  d = w123 + 1048576; o = i - 262144; }
    else if (i < 1179648) { s = wh;  d = whB;            o = i - 393216; }
    else if (i < 2228224) { s = wd1; d = wd1B;           o = i - 1179648; }
    else                  { s = wd2; d = wd2B;           o = i - 2228224; ns = 512000; }
    bf16x4 v;
    if (o < ns) {
      float4 f = ((const float4*)s)[o];
      v[0] = (bf16_t)f.x; v[1] = (bf16_t)f.y; v[2] = (bf16_t)f.z; v[3] = (bf16_t)f.w;
    } else {
      v[0] = (bf16_t)0.0f; v[1] = (bf16_t)0.0f; v[2] = (bf16_t)0.0f; v[3] = (bf16_t)0.0f;
    }
    *(bf16x4*)(d + (size_t)o * 4) = v;
  }
}

__global__ void concat_bias3(const float* __restrict__ a, const float* __restrict__ b,
                             const float* __restrict__ c, float* __restrict__ dst) {
  int i = blockIdx.x * blockDim.x + threadIdx.x;
  if (i < 1024) dst[i] = a[i];
  else if (i < 2048) dst[i] = b[i - 1024];
  else if (i < 3072) dst[i] = c[i - 2048];
}

// ---------------- GEMM: C = act(A @ Bw^T + bias), 256x256 tile ----------------
// 512 threads = 8 waves (2 M x 4 N), wave tile 128x64 = acc[8][4] 16x16 frags.
// LDS: SLOTS-deep ring of (A 256x32 + B 256x32) bf16; staging + XOR swizzle
// verified conflict-free (R2). SLOTS=4: R2-exact counted-vmcnt schedule.
// SLOTS=2: stage-at-top, MFMA, then vmcnt(0)+lgkm(0)+barrier (span covers
// HBM latency; residual hidden by 2nd resident block).
template<int SLOTS, bool BDIAG, bool RELU, bool OUT_BF16>
__global__ __launch_bounds__(512, (SLOTS == 2 ? 4 : 2))
void gemm256(const bf16_t* __restrict__ A, int lda,
             const bf16_t* __restrict__ Bw, int ldb,
             const float* __restrict__ bias,
             void* __restrict__ Cout, int ldc,
             int K, int Nmask, int nbx)
{
  extern __shared__ char lds[];
  bf16_t* Ab = (bf16_t*)lds;                         // SLOTS x 16 KiB
  bf16_t* Bb = (bf16_t*)(lds + SLOTS * 16384);

  const int t   = threadIdx.x;
  const int ln  = t & 63;
  const int w   = t >> 6;
  const int l15 = ln & 15, lhi = ln >> 4;
  const int wm  = w >> 2, wn = w & 3;

  // XCD-chunked block swizzle (grid divisible by 8)
  const int nb = (int)gridDim.x;
  const int id = (int)blockIdx.x;
  const int id_sw = (id & 7) * (nb >> 3) + (id >> 3);
  const int bx = id_sw % nbx, by = id_sw / nbx;
  const int rowBase = by * 256;
  const int colBase = bx * 256;
  const int aCol0 = BDIAG ? (colBase >> 10) * 512 : 0;

  // staging: thread t -> LDS linear byte i*8192 + w*1024 + ln*16
  //   (row = i*128 + w*16 + ln/4); source col granule pre-swizzled involution.
  const int srow = (w << 4) + (ln >> 2);
  const int scol = (((ln & 3) ^ (ln >> 3)) & 3) << 3;

  const bf16_t* aS = A  + (size_t)(rowBase + srow) * lda + aCol0 + scol;
  const bf16_t* bS = Bw + (size_t)(colBase + srow) * ldb + scol;
  const size_t aI = (size_t)128 * lda;
  const size_t bI = (size_t)128 * ldb;
  bf16_t* daW = Ab + (w << 9);
  bf16_t* dbW = Bb + (w << 9);

  // fragment read offsets (elements), swizzle involution re-applied
  const int key  = (l15 >> 1) & 3;
  const int fcol = (lhi ^ key) << 3;
  const int aOff = (wm * 128 + l15) * 32 + fcol;   // + mf*512 + slot*8192
  const int bOff = (wn * 64  + l15) * 32 + fcol;   // + nf*512 + slot*8192

  const int nt = K >> 5;

  f32x4 acc[8][4] = {};

  #define STAGE(kt, s)                                                              \
    do {                                                                            \
      const bf16_t* a_ = aS + (size_t)(kt) * 32;                                    \
      const bf16_t* b_ = bS + (size_t)(kt) * 32;                                    \
      bf16_t* da_ = daW + (s) * 8192;                                               \
      bf16_t* db_ = dbW + (s) * 8192;                                               \
      __builtin_amdgcn_global_load_lds(AS1(a_),      AS3(da_),        16, 0, 0);    \
      __builtin_amdgcn_global_load_lds(AS1(a_ + aI), AS3(da_ + 4096), 16, 0, 0);    \
      __builtin_amdgcn_global_load_lds(AS1(b_),      AS3(db_),        16, 0, 0);    \
      __builtin_amdgcn_global_load_lds(AS1(b_ + bI), AS3(db_ + 4096), 16, 0, 0);    \
    } while (0)

  if (SLOTS == 4) {
    // prologue: stage tiles 0..2, confirm tile 0 (8 = tiles 1,2 in flight)
    STAGE(0, 0); STAGE(1, 1); STAGE(2, 2);
    asm volatile("s_waitcnt vmcnt(8)" ::: "memory");
  } else {
    STAGE(0, 0);
    asm volatile("s_waitcnt vmcnt(0)" ::: "memory");
  }
  __builtin_amdgcn_s_barrier();
  asm volatile("" ::: "memory");

  for (int j = 0; j < nt; ++j) {
    const int s = j & (SLOTS - 1);
    const bf16_t* As_ = Ab + s * 8192 + aOff;
    const bf16_t* Bs_ = Bb + s * 8192 + bOff;

    if (SLOTS == 4) {
      // ---- R2-exact: reads; stage j+3; counted waits; lgkm0; barrier; MFMA ----
      bf16x8 af[8], bfr[4];
      #pragma unroll
      for (int mf = 0; mf < 8; ++mf) af[mf] = *(const bf16x8*)(As_ + mf * 512);
      #pragma unroll
      for (int nf = 0; nf < 4; ++nf) bfr[nf] = *(const bf16x8*)(Bs_ + nf * 512);

      if (j + 3 < nt) {
        STAGE(j + 3, ((j + 3) & 3));
        asm volatile("s_waitcnt vmcnt(8)" ::: "memory");   // tile j+1 arrived
      } else if (j + 2 < nt) {
        asm volatile("s_waitcnt vmcnt(4)" ::: "memory");
      } else if (j + 1 < nt) {
        asm volatile("s_waitcnt vmcnt(0)" ::: "memory");
      }
      asm volatile("s_waitcnt lgkmcnt(0)" ::: "memory");
      __builtin_amdgcn_s_barrier();
      asm volatile("" ::: "memory");

      __builtin_amdgcn_s_setprio(1);
      #pragma unroll
      for (int mf = 0; mf < 8; ++mf)
        #pragma unroll
        for (int nf = 0; nf < 4; ++nf)
          acc[mf][nf] = __builtin_amdgcn_mfma_f32_16x16x32_bf16(af[mf], bfr[nf], acc[mf][nf], 0, 0, 0);
      __builtin_amdgcn_s_setprio(0);
    } else {
      // ---- 2-slot: stage j+1 at top; reads; MFMA; drain; barrier ----
      if (j + 1 < nt) STAGE(j + 1, s ^ 1);

      bf16x8 af[8], bfr[4];
      #pragma unroll
      for (int mf = 0; mf < 8; ++mf) af[mf] = *(const bf16x8*)(As_ + mf * 512);
      #pragma unroll
      for (int nf = 0; nf < 4; ++nf) bfr[nf] = *(const bf16x8*)(Bs_ + nf * 512);

      __builtin_amdgcn_s_setprio(1);
      #pragma unroll
      for (int mf = 0; mf < 8; ++mf)
        #pragma unroll
        for (int nf = 0; nf < 4; ++nf)
          acc[mf][nf] = __builtin_amdgcn_mfma_f32_16x16x32_bf16(af[mf], bfr[nf], acc[mf][nf], 0, 0, 0);
      __builtin_amdgcn_s_setprio(0);

      if (j + 1 < nt) {
        // RAW: confirm tile j+1 (issued this iter; span ~full tile > HBM lat).
        // WAR: lgkm(0) drains this iter's slot-s reads before barrier; slot s
        // is overwritten only at top of iter j+1 (after this barrier).
        asm volatile("s_waitcnt vmcnt(0)" ::: "memory");
        asm volatile("s_waitcnt lgkmcnt(0)" ::: "memory");
        __builtin_amdgcn_s_barrier();
        asm volatile("" ::: "memory");
      }
    }
  }
  #undef STAGE

  // epilogue: C/D layout col=l15, row=lhi*4+i (verified)
  #pragma unroll
  for (int mf = 0; mf < 8; ++mf) {
    const int row = rowBase + wm * 128 + mf * 16 + lhi * 4;
    #pragma unroll
    for (int nf = 0; nf < 4; ++nf) {
      const int col = colBase + wn * 64 + nf * 16 + l15;
      const float bv = (col < Nmask) ? bias[col] : 0.0f;
      #pragma unroll
      for (int i = 0; i < 4; ++i) {
        float v = acc[mf][nf][i] + bv;
        if (RELU) v = fmaxf(v, 0.0f);
        if (OUT_BF16) {
          ((bf16_t*)Cout)[(size_t)(row + i) * ldc + col] = (bf16_t)v;
        } else {
          if (col < Nmask) ((float*)Cout)[(size_t)(row + i) * ldc + col] = v;
        }
      }
    }
  }
}

// ---------------- alphas -> softmax -> context (one block per row) ----------------
__global__ __launch_bounds__(256)
void attn_ctx(const bf16_t* __restrict__ P, bf16_t* __restrict__ ds) {
  __shared__ float red[3][4];
  __shared__ float wsh[3];
  const int r = blockIdx.x;
  const int t = threadIdx.x;
  const bf16_t* Prow = P + (size_t)r * 3072;
  bf16_t* dsrow = ds + (size_t)r * 2048;

  const int j = t * 4;
  bf16x4 lv = *(const bf16x4*)(dsrow + 1024 + j);
  float lhv[4], pv[3][4];
  float s[3] = {0.f, 0.f, 0.f};
  #pragma unroll
  for (int q = 0; q < 4; q++) lhv[q] = (float)lv[q];
  #pragma unroll
  for (int e = 0; e < 3; e++) {
    bf16x4 p = *(const bf16x4*)(Prow + e * 1024 + j);
    #pragma unroll
    for (int q = 0; q < 4; q++) {
      pv[e][q] = (float)p[q];
      s[e] += lhv[q] * pv[e][q];
    }
  }
  #pragma unroll
  for (int off = 32; off > 0; off >>= 1) {
    #pragma unroll
    for (int e = 0; e < 3; e++) s[e] += __shfl_down(s[e], off, 64);
  }
  const int w = t >> 6, l = t & 63;
  if (l == 0) {
    #pragma unroll
    for (int e = 0; e < 3; e++) red[e][w] = s[e];
  }
  __syncthreads();
  if (t == 0) {
    float a0 = red[0][0] + red[0][1] + red[0][2] + red[0][3];
    float a1 = red[1][0] + red[1][1] + red[1][2] + red[1][3];
    float a2 = red[2][0] + red[2][1] + red[2][2] + red[2][3];
    float mx = fmaxf(a0, fmaxf(a1, a2));
    float e0 = expf(a0 - mx), e1 = expf(a1 - mx), e2 = expf(a2 - mx);
    float inv = 1.0f / (e0 + e1 + e2);
    wsh[0] = e0 * inv; wsh[1] = e1 * inv; wsh[2] = e2 * inv;
  }
  __syncthreads();
  const float w0 = wsh[0], w1 = wsh[1], w2 = wsh[2];
  bf16x4 o;
  #pragma unroll
  for (int q = 0; q < 4; q++)
    o[q] = (bf16_t)(w0 * pv[0][q] + w1 * pv[1][q] + w2 * pv[2][q]);
  *(bf16x4*)(dsrow + j) = o;
}

// ---------------- launch ----------------
extern "C" void kernel_launch(void* const* d_in, const int* in_sizes, int n_in,
                              void* d_out, int out_size, void* d_ws, size_t ws_size,
                              hipStream_t stream) {
  (void)in_sizes; (void)n_in; (void)out_size; (void)ws_size;

  const float* tube = (const float*)d_in[0];
  const float* w1W  = (const float*)d_in[1];
  const float* w1b  = (const float*)d_in[2];
  const float* w2W  = (const float*)d_in[3];
  const float* w2b  = (const float*)d_in[4];
  const float* w3W  = (const float*)d_in[5];
  const float* w3b  = (const float*)d_in[6];
  const float* whW  = (const float*)d_in[7];
  const float* whb  = (const float*)d_in[8];
  const float* wd1W = (const float*)d_in[9];
  const float* wd1b = (const float*)d_in[10];
  const float* wd2W = (const float*)d_in[11];
  const float* wd2b = (const float*)d_in[12];

  // workspace layout (bytes); out1 aliases {whB, w123B, tubeB} which are dead by G4.
  char* ws = (char*)d_ws;
  bf16_t* P       = (bf16_t*)(ws + 0);            // 16384x3072
  bf16_t* ds      = (bf16_t*)(ws + 100663296);    // 16384x2048
  bf16_t* wd1B    = (bf16_t*)(ws + 167772160);    // 2048x2048
  bf16_t* wd2B    = (bf16_t*)(ws + 176160768);    // 1024x2048 (rows 1000.. zero)
  bf16_t* whB     = (bf16_t*)(ws + 180355072);    // 1024x3072
  bf16_t* w123B   = (bf16_t*)(ws + 186646528);    // 3072x512
  bf16_t* tubeB   = (bf16_t*)(ws + 189792256);    // 16384x1536
  bf16_t* out1    = (bf16_t*)(ws + 180355072);    // 16384x2048, aliases whB..tubeB
  float*  bias123 = (float*)(ws + 247463936);     // 3072 f32

  hipFuncSetAttribute((const void*)(gemm256<2, true,  true,  true >),
                      hipFuncAttributeMaxDynamicSharedMemorySize, 65536);
  hipFuncSetAttribute((const void*)(gemm256<2, false, true,  true >),
                      hipFuncAttributeMaxDynamicSharedMemorySize, 65536);
  hipFuncSetAttribute((const void*)(gemm256<4, false, true,  true >),
                      hipFuncAttributeMaxDynamicSharedMemorySize, 131072);
  hipFuncSetAttribute((const void*)(gemm256<4, false, false, false>),
                      hipFuncAttributeMaxDynamicSharedMemorySize, 131072);

  // conversions: tube (big, separate) + all weights (one launch)
  hipLaunchKernelGGL(cvt_f32_bf16_v4, dim3(2048), dim3(256), 0, stream,
                     tube, tubeB, 6291456, 6291456);
  hipLaunchKernelGGL(cvt_weights, dim3(2048), dim3(256), 0, stream,
                     w1W, w2W, w3W, whW, wd1W, wd2W, w123B, whB, wd1B, wd2B);
  hipLaunchKernelGGL(concat_bias3, dim3(12), dim3(256), 0, stream, w1b, w2b, w3b, bias123);

  // G1: P = relu(block-diag expert GEMM), N=3072, K=512   [768 blocks = 3/CU -> SLOTS=2]
  hipLaunchKernelGGL((gemm256<2, true, true, true>), dim3(12 * 64), dim3(512), 65536, stream,
                     tubeB, 1536, w123B, 512, bias123, (void*)P, 3072, 512, 3072, 12);
  // G2: ds[:,1024:2048] = relu(P @ wh^T + b), N=1024, K=3072  [256 blocks = 1/CU -> SLOTS=4]
  hipLaunchKernelGGL((gemm256<4, false, true, true>), dim3(4 * 64), dim3(512), 131072, stream,
                     P, 3072, whB, 3072, whb, (void*)(ds + 1024), 2048, 3072, 1024, 4);
  // attn: alphas -> softmax -> context into ds[:,0:1024]
  hipLaunchKernelGGL(attn_ctx, dim3(16384), dim3(256), 0, stream, P, ds);
  // G4: out1 = relu(ds @ wd1^T + b), N=2048, K=2048   [512 blocks = 2/CU -> SLOTS=2]
  hipLaunchKernelGGL((gemm256<2, false, true, true>), dim3(8 * 64), dim3(512), 65536, stream,
                     ds, 2048, wd1B, 2048, wd1b, (void*)out1, 2048, 2048, 2048, 8);
  // G5: out = out1 @ wd2^T + b (fp32, N masked to 1000), K=2048  [256 blocks -> SLOTS=4]
  hipLaunchKernelGGL((gemm256<4, false, false, false>), dim3(4 * 64), dim3(512), 131072, stream,
                     out1, 2048, wd2B, 2048, wd2b, d_out, 1000, 2048, 1000, 4);
}

// Round 15
// 421.452 us; speedup vs baseline: 5.5043x; 5.5043x over previous
//
#include <hip/hip_runtime.h>
#include <hip/hip_bf16.h>

// ClassAtt fused pipeline. R15 = R14 with the spill bug fixed: SLOTS=2
// instantiations use __launch_bounds__(512,2) (NOT 4) so the compiler keeps
// ~100 VGPRs (no spill); 64 KiB LDS then lets the HW co-schedule 2 blocks/CU
// at runtime (VGPR 100 <= 128 allows 4 waves/EU). Clean m114 occupancy test.
//   SLOTS=4: R2-exact schedule (128 KiB LDS, 1 block/CU)  -> G2, G5
//   SLOTS=2: 64 KiB LDS, stage-at-top + end drain          -> G1, G4

typedef __bf16 bf16_t;
typedef __bf16 bf16x4 __attribute__((ext_vector_type(4)));
typedef __bf16 bf16x8 __attribute__((ext_vector_type(8)));
typedef float  f32x4  __attribute__((ext_vector_type(4)));

#define AS1(p) (const __attribute__((address_space(1))) void*)(p)
#define AS3(p) (__attribute__((address_space(3))) void*)(p)

// ---------------- f32 -> bf16 conversion (tube) ----------------
__global__ void cvt_f32_bf16_v4(const float* __restrict__ src, bf16_t* __restrict__ dst,
                                int n4src, int n4tot) {
  for (int i = blockIdx.x * blockDim.x + threadIdx.x; i < n4tot; i += gridDim.x * blockDim.x) {
    bf16x4 o;
    if (i < n4src) {
      float4 f = ((const float4*)src)[i];
      o[0] = (bf16_t)f.x; o[1] = (bf16_t)f.y; o[2] = (bf16_t)f.z; o[3] = (bf16_t)f.w;
    } else {
      o[0] = (bf16_t)0.0f; o[1] = (bf16_t)0.0f; o[2] = (bf16_t)0.0f; o[3] = (bf16_t)0.0f;
    }
    *(bf16x4*)(dst + (size_t)i * 4) = o;
  }
}

// ---------------- all weight cvts merged (one launch; verified) ----------
__global__ void cvt_weights(const float* __restrict__ w1, const float* __restrict__ w2,
                            const float* __restrict__ w3, const float* __restrict__ wh,
                            const float* __restrict__ wd1, const float* __restrict__ wd2,
                            bf16_t* __restrict__ w123, bf16_t* __restrict__ whB,
                            bf16_t* __restrict__ wd1B, bf16_t* __restrict__ wd2B) {
  const int stride = gridDim.x * blockDim.x;
  for (int i = blockIdx.x * blockDim.x + threadIdx.x; i < 2752512; i += stride) {
    const float* s; bf16_t* d; int o; int ns = 1 << 30;
    if (i < 131072)       { s = w1;  d = w123;           o = i; }
    else if (i < 262144)  { s = w2;  d = w123 + 524288;  o = i - 131072; }
    else if (i < 393216)  { s = w3;  d = w123 + 1048576; o = i - 262144; }
    else if (i < 1179648) { s = wh;  d = whB;            o = i - 393216; }
    else if (i < 2228224) { s = wd1; d = wd1B;           o = i - 1179648; }
    else                  { s = wd2; d = wd2B;           o = i - 2228224; ns = 512000; }
    bf16x4 v;
    if (o < ns) {
      float4 f = ((const float4*)s)[o];
      v[0] = (bf16_t)f.x; v[1] = (bf16_t)f.y; v[2] = (bf16_t)f.z; v[3] = (bf16_t)f.w;
    } else {
      v[0] = (bf16_t)0.0f; v[1] = (bf16_t)0.0f; v[2] = (bf16_t)0.0f; v[3] = (bf16_t)0.0f;
    }
    *(bf16x4*)(d + (size_t)o * 4) = v;
  }
}

__global__ void concat_bias3(const float* __restrict__ a, const float* __restrict__ b,
                             const float* __restrict__ c, float* __restrict__ dst) {
  int i = blockIdx.x * blockDim.x + threadIdx.x;
  if (i < 1024) dst[i] = a[i];
  else if (i < 2048) dst[i] = b[i - 1024];
  else if (i < 3072) dst[i] = c[i - 2048];
}

// ---------------- GEMM: C = act(A @ Bw^T + bias), 256x256 tile ----------------
// 512 threads = 8 waves (2 M x 4 N), wave tile 128x64 = acc[8][4] 16x16 frags.
// LDS: SLOTS-deep ring of (A 256x32 + B 256x32) bf16; staging + XOR swizzle
// verified conflict-free (R2). SLOTS=4: R2-exact counted-vmcnt schedule.
// SLOTS=2: stage-at-top, reads, MFMA, then vmcnt(0)+lgkm(0)+barrier; drain
// latency covered by MFMA cluster + the 2nd co-resident block (m114).
template<int SLOTS, bool BDIAG, bool RELU, bool OUT_BF16>
__global__ __launch_bounds__(512, 2)
void gemm256(const bf16_t* __restrict__ A, int lda,
             const bf16_t* __restrict__ Bw, int ldb,
             const float* __restrict__ bias,
             void* __restrict__ Cout, int ldc,
             int K, int Nmask, int nbx)
{
  extern __shared__ char lds[];
  bf16_t* Ab = (bf16_t*)lds;                         // SLOTS x 16 KiB
  bf16_t* Bb = (bf16_t*)(lds + SLOTS * 16384);

  const int t   = threadIdx.x;
  const int ln  = t & 63;
  const int w   = t >> 6;
  const int l15 = ln & 15, lhi = ln >> 4;
  const int wm  = w >> 2, wn = w & 3;

  // XCD-chunked block swizzle (grid divisible by 8)
  const int nb = (int)gridDim.x;
  const int id = (int)blockIdx.x;
  const int id_sw = (id & 7) * (nb >> 3) + (id >> 3);
  const int bx = id_sw % nbx, by = id_sw / nbx;
  const int rowBase = by * 256;
  const int colBase = bx * 256;
  const int aCol0 = BDIAG ? (colBase >> 10) * 512 : 0;

  // staging: thread t -> LDS linear byte i*8192 + w*1024 + ln*16
  //   (row = i*128 + w*16 + ln/4); source col granule pre-swizzled involution.
  const int srow = (w << 4) + (ln >> 2);
  const int scol = (((ln & 3) ^ (ln >> 3)) & 3) << 3;

  const bf16_t* aS = A  + (size_t)(rowBase + srow) * lda + aCol0 + scol;
  const bf16_t* bS = Bw + (size_t)(colBase + srow) * ldb + scol;
  const size_t aI = (size_t)128 * lda;
  const size_t bI = (size_t)128 * ldb;
  bf16_t* daW = Ab + (w << 9);
  bf16_t* dbW = Bb + (w << 9);

  // fragment read offsets (elements), swizzle involution re-applied
  const int key  = (l15 >> 1) & 3;
  const int fcol = (lhi ^ key) << 3;
  const int aOff = (wm * 128 + l15) * 32 + fcol;   // + mf*512 + slot*8192
  const int bOff = (wn * 64  + l15) * 32 + fcol;   // + nf*512 + slot*8192

  const int nt = K >> 5;

  f32x4 acc[8][4] = {};

  #define STAGE(kt, s)                                                              \
    do {                                                                            \
      const bf16_t* a_ = aS + (size_t)(kt) * 32;                                    \
      const bf16_t* b_ = bS + (size_t)(kt) * 32;                                    \
      bf16_t* da_ = daW + (s) * 8192;                                               \
      bf16_t* db_ = dbW + (s) * 8192;                                               \
      __builtin_amdgcn_global_load_lds(AS1(a_),      AS3(da_),        16, 0, 0);    \
      __builtin_amdgcn_global_load_lds(AS1(a_ + aI), AS3(da_ + 4096), 16, 0, 0);    \
      __builtin_amdgcn_global_load_lds(AS1(b_),      AS3(db_),        16, 0, 0);    \
      __builtin_amdgcn_global_load_lds(AS1(b_ + bI), AS3(db_ + 4096), 16, 0, 0);    \
    } while (0)

  if (SLOTS == 4) {
    // prologue: stage tiles 0..2, confirm tile 0 (8 = tiles 1,2 in flight)
    STAGE(0, 0); STAGE(1, 1); STAGE(2, 2);
    asm volatile("s_waitcnt vmcnt(8)" ::: "memory");
  } else {
    STAGE(0, 0);
    asm volatile("s_waitcnt vmcnt(0)" ::: "memory");
  }
  __builtin_amdgcn_s_barrier();
  asm volatile("" ::: "memory");

  for (int j = 0; j < nt; ++j) {
    const int s = j & (SLOTS - 1);
    const bf16_t* As_ = Ab + s * 8192 + aOff;
    const bf16_t* Bs_ = Bb + s * 8192 + bOff;

    if (SLOTS == 4) {
      // ---- R2-exact: reads; stage j+3; counted waits; lgkm0; barrier; MFMA ----
      bf16x8 af[8], bfr[4];
      #pragma unroll
      for (int mf = 0; mf < 8; ++mf) af[mf] = *(const bf16x8*)(As_ + mf * 512);
      #pragma unroll
      for (int nf = 0; nf < 4; ++nf) bfr[nf] = *(const bf16x8*)(Bs_ + nf * 512);

      if (j + 3 < nt) {
        STAGE(j + 3, ((j + 3) & 3));
        asm volatile("s_waitcnt vmcnt(8)" ::: "memory");   // tile j+1 arrived
      } else if (j + 2 < nt) {
        asm volatile("s_waitcnt vmcnt(4)" ::: "memory");
      } else if (j + 1 < nt) {
        asm volatile("s_waitcnt vmcnt(0)" ::: "memory");
      }
      asm volatile("s_waitcnt lgkmcnt(0)" ::: "memory");
      __builtin_amdgcn_s_barrier();
      asm volatile("" ::: "memory");

      __builtin_amdgcn_s_setprio(1);
      #pragma unroll
      for (int mf = 0; mf < 8; ++mf)
        #pragma unroll
        for (int nf = 0; nf < 4; ++nf)
          acc[mf][nf] = __builtin_amdgcn_mfma_f32_16x16x32_bf16(af[mf], bfr[nf], acc[mf][nf], 0, 0, 0);
      __builtin_amdgcn_s_setprio(0);
    } else {
      // ---- 2-slot: stage j+1 at top; reads; MFMA; drain; barrier ----
      if (j + 1 < nt) STAGE(j + 1, s ^ 1);

      bf16x8 af[8], bfr[4];
      #pragma unroll
      for (int mf = 0; mf < 8; ++mf) af[mf] = *(const bf16x8*)(As_ + mf * 512);
      #pragma unroll
      for (int nf = 0; nf < 4; ++nf) bfr[nf] = *(const bf16x8*)(Bs_ + nf * 512);

      __builtin_amdgcn_s_setprio(1);
      #pragma unroll
      for (int mf = 0; mf < 8; ++mf)
        #pragma unroll
        for (int nf = 0; nf < 4; ++nf)
          acc[mf][nf] = __builtin_amdgcn_mfma_f32_16x16x32_bf16(af[mf], bfr[nf], acc[mf][nf], 0, 0, 0);
      __builtin_amdgcn_s_setprio(0);

      if (j + 1 < nt) {
        // RAW: confirm tile j+1 (issued at iter top; MFMA cluster + 2nd block
        // cover the latency). WAR: lgkm(0) drains slot-s reads before barrier.
        asm volatile("s_waitcnt vmcnt(0)" ::: "memory");
        asm volatile("s_waitcnt lgkmcnt(0)" ::: "memory");
        __builtin_amdgcn_s_barrier();
        asm volatile("" ::: "memory");
      }
    }
  }
  #undef STAGE

  // epilogue: C/D layout col=l15, row=lhi*4+i (verified)
  #pragma unroll
  for (int mf = 0; mf < 8; ++mf) {
    const int row = rowBase + wm * 128 + mf * 16 + lhi * 4;
    #pragma unroll
    for (int nf = 0; nf < 4; ++nf) {
      const int col = colBase + wn * 64 + nf * 16 + l15;
      const float bv = (col < Nmask) ? bias[col] : 0.0f;
      #pragma unroll
      for (int i = 0; i < 4; ++i) {
        float v = acc[mf][nf][i] + bv;
        if (RELU) v = fmaxf(v, 0.0f);
        if (OUT_BF16) {
          ((bf16_t*)Cout)[(size_t)(row + i) * ldc + col] = (bf16_t)v;
        } else {
          if (col < Nmask) ((float*)Cout)[(size_t)(row + i) * ldc + col] = v;
        }
      }
    }
  }
}

// ---------------- alphas -> softmax -> context (one block per row) ----------------
__global__ __launch_bounds__(256)
void attn_ctx(const bf16_t* __restrict__ P, bf16_t* __restrict__ ds) {
  __shared__ float red[3][4];
  __shared__ float wsh[3];
  const int r = blockIdx.x;
  const int t = threadIdx.x;
  const bf16_t* Prow = P + (size_t)r * 3072;
  bf16_t* dsrow = ds + (size_t)r * 2048;

  const int j = t * 4;
  bf16x4 lv = *(const bf16x4*)(dsrow + 1024 + j);
  float lhv[4], pv[3][4];
  float s[3] = {0.f, 0.f, 0.f};
  #pragma unroll
  for (int q = 0; q < 4; q++) lhv[q] = (float)lv[q];
  #pragma unroll
  for (int e = 0; e < 3; e++) {
    bf16x4 p = *(const bf16x4*)(Prow + e * 1024 + j);
    #pragma unroll
    for (int q = 0; q < 4; q++) {
      pv[e][q] = (float)p[q];
      s[e] += lhv[q] * pv[e][q];
    }
  }
  #pragma unroll
  for (int off = 32; off > 0; off >>= 1) {
    #pragma unroll
    for (int e = 0; e < 3; e++) s[e] += __shfl_down(s[e], off, 64);
  }
  const int w = t >> 6, l = t & 63;
  if (l == 0) {
    #pragma unroll
    for (int e = 0; e < 3; e++) red[e][w] = s[e];
  }
  __syncthreads();
  if (t == 0) {
    float a0 = red[0][0] + red[0][1] + red[0][2] + red[0][3];
    float a1 = red[1][0] + red[1][1] + red[1][2] + red[1][3];
    float a2 = red[2][0] + red[2][1] + red[2][2] + red[2][3];
    float mx = fmaxf(a0, fmaxf(a1, a2));
    float e0 = expf(a0 - mx), e1 = expf(a1 - mx), e2 = expf(a2 - mx);
    float inv = 1.0f / (e0 + e1 + e2);
    wsh[0] = e0 * inv; wsh[1] = e1 * inv; wsh[2] = e2 * inv;
  }
  __syncthreads();
  const float w0 = wsh[0], w1 = wsh[1], w2 = wsh[2];
  bf16x4 o;
  #pragma unroll
  for (int q = 0; q < 4; q++)
    o[q] = (bf16_t)(w0 * pv[0][q] + w1 * pv[1][q] + w2 * pv[2][q]);
  *(bf16x4*)(dsrow + j) = o;
}

// ---------------- launch ----------------
extern "C" void kernel_launch(void* const* d_in, const int* in_sizes, int n_in,
                              void* d_out, int out_size, void* d_ws, size_t ws_size,
                              hipStream_t stream) {
  (void)in_sizes; (void)n_in; (void)out_size; (void)ws_size;

  const float* tube = (const float*)d_in[0];
  const float* w1W  = (const float*)d_in[1];
  const float* w1b  = (const float*)d_in[2];
  const float* w2W  = (const float*)d_in[3];
  const float* w2b  = (const float*)d_in[4];
  const float* w3W  = (const float*)d_in[5];
  const float* w3b  = (const float*)d_in[6];
  const float* whW  = (const float*)d_in[7];
  const float* whb  = (const float*)d_in[8];
  const float* wd1W = (const float*)d_in[9];
  const float* wd1b = (const float*)d_in[10];
  const float* wd2W = (const float*)d_in[11];
  const float* wd2b = (const float*)d_in[12];

  // workspace layout (bytes); out1 aliases {whB, w123B, tubeB} which are dead by G4.
  char* ws = (char*)d_ws;
  bf16_t* P       = (bf16_t*)(ws + 0);            // 16384x3072
  bf16_t* ds      = (bf16_t*)(ws + 100663296);    // 16384x2048
  bf16_t* wd1B    = (bf16_t*)(ws + 167772160);    // 2048x2048
  bf16_t* wd2B    = (bf16_t*)(ws + 176160768);    // 1024x2048 (rows 1000.. zero)
  bf16_t* whB     = (bf16_t*)(ws + 180355072);    // 1024x3072
  bf16_t* w123B   = (bf16_t*)(ws + 186646528);    // 3072x512
  bf16_t* tubeB   = (bf16_t*)(ws + 189792256);    // 16384x1536
  bf16_t* out1    = (bf16_t*)(ws + 180355072);    // 16384x2048, aliases whB..tubeB
  float*  bias123 = (float*)(ws + 247463936);     // 3072 f32

  hipFuncSetAttribute((const void*)(gemm256<2, true,  true,  true >),
                      hipFuncAttributeMaxDynamicSharedMemorySize, 65536);
  hipFuncSetAttribute((const void*)(gemm256<2, false, true,  true >),
                      hipFuncAttributeMaxDynamicSharedMemorySize, 65536);
  hipFuncSetAttribute((const void*)(gemm256<4, false, true,  true >),
                      hipFuncAttributeMaxDynamicSharedMemorySize, 131072);
  hipFuncSetAttribute((const void*)(gemm256<4, false, false, false>),
                      hipFuncAttributeMaxDynamicSharedMemorySize, 131072);

  // conversions: tube (big, separate) + all weights (one launch)
  hipLaunchKernelGGL(cvt_f32_bf16_v4, dim3(2048), dim3(256), 0, stream,
                     tube, tubeB, 6291456, 6291456);
  hipLaunchKernelGGL(cvt_weights, dim3(2048), dim3(256), 0, stream,
                     w1W, w2W, w3W, whW, wd1W, wd2W, w123B, whB, wd1B, wd2B);
  hipLaunchKernelGGL(concat_bias3, dim3(12), dim3(256), 0, stream, w1b, w2b, w3b, bias123);

  // G1: P = relu(block-diag expert GEMM), N=3072, K=512   [768 blocks -> SLOTS=2, 2/CU]
  hipLaunchKernelGGL((gemm256<2, true, true, true>), dim3(12 * 64), dim3(512), 65536, stream,
                     tubeB, 1536, w123B, 512, bias123, (void*)P, 3072, 512, 3072, 12);
  // G2: ds[:,1024:2048] = relu(P @ wh^T + b), N=1024, K=3072  [256 blocks -> SLOTS=4]
  hipLaunchKernelGGL((gemm256<4, false, true, true>), dim3(4 * 64), dim3(512), 131072, stream,
                     P, 3072, whB, 3072, whb, (void*)(ds + 1024), 2048, 3072, 1024, 4);
  // attn: alphas -> softmax -> context into ds[:,0:1024]
  hipLaunchKernelGGL(attn_ctx, dim3(16384), dim3(256), 0, stream, P, ds);
  // G4: out1 = relu(ds @ wd1^T + b), N=2048, K=2048   [512 blocks -> SLOTS=2, 2/CU]
  hipLaunchKernelGGL((gemm256<2, false, true, true>), dim3(8 * 64), dim3(512), 65536, stream,
                     ds, 2048, wd1B, 2048, wd1b, (void*)out1, 2048, 2048, 2048, 8);
  // G5: out = out1 @ wd2^T + b (fp32, N masked to 1000), K=2048  [256 blocks -> SLOTS=4]
  hipLaunchKernelGGL((gemm256<4, false, false, false>), dim3(4 * 64), dim3(512), 131072, stream,
                     out1, 2048, wd2B, 2048, wd2b, d_out, 1000, 2048, 1000, 4);
}

// Round 16
// 414.171 us; speedup vs baseline: 5.6011x; 1.0176x over previous
//
#include <hip/hip_runtime.h>
#include <hip/hip_bf16.h>

// ClassAtt fused pipeline. R16 = R13 baseline (R2-exact gemm256 for G1/G2/G5)
// + NEW gemm256k64 for G4 (within-bench A/B):
//   BK=64, 2-slot ring (128 KiB), ONE barrier per 64-K tile, stage-at-top,
//   no barrier between a tile's reads and MFMAs (ks1 reads overlap ks0 MFMA),
//   vmcnt(0) drain covered by ~2500-cyc MFMA span. Swizzle: byte ^= (row&7)<<4
//   (guide G4 recipe for 128-B rows), pre-applied on source, re-applied on read.

typedef __bf16 bf16_t;
typedef __bf16 bf16x4 __attribute__((ext_vector_type(4)));
typedef __bf16 bf16x8 __attribute__((ext_vector_type(8)));
typedef float  f32x4  __attribute__((ext_vector_type(4)));

#define AS1(p) (const __attribute__((address_space(1))) void*)(p)
#define AS3(p) (__attribute__((address_space(3))) void*)(p)

// ---------------- f32 -> bf16 conversion (tube) ----------------
__global__ void cvt_f32_bf16_v4(const float* __restrict__ src, bf16_t* __restrict__ dst,
                                int n4src, int n4tot) {
  for (int i = blockIdx.x * blockDim.x + threadIdx.x; i < n4tot; i += gridDim.x * blockDim.x) {
    bf16x4 o;
    if (i < n4src) {
      float4 f = ((const float4*)src)[i];
      o[0] = (bf16_t)f.x; o[1] = (bf16_t)f.y; o[2] = (bf16_t)f.z; o[3] = (bf16_t)f.w;
    } else {
      o[0] = (bf16_t)0.0f; o[1] = (bf16_t)0.0f; o[2] = (bf16_t)0.0f; o[3] = (bf16_t)0.0f;
    }
    *(bf16x4*)(dst + (size_t)i * 4) = o;
  }
}

// ---------------- all weight cvts merged (one launch; verified) ----------
__global__ void cvt_weights(const float* __restrict__ w1, const float* __restrict__ w2,
                            const float* __restrict__ w3, const float* __restrict__ wh,
                            const float* __restrict__ wd1, const float* __restrict__ wd2,
                            bf16_t* __restrict__ w123, bf16_t* __restrict__ whB,
                            bf16_t* __restrict__ wd1B, bf16_t* __restrict__ wd2B) {
  const int stride = gridDim.x * blockDim.x;
  for (int i = blockIdx.x * blockDim.x + threadIdx.x; i < 2752512; i += stride) {
    const float* s; bf16_t* d; int o; int ns = 1 << 30;
    if (i < 131072)       { s = w1;  d = w123;           o = i; }
    else if (i < 262144)  { s = w2;  d = w123 + 524288;  o = i - 131072; }
    else if (i < 393216)  { s = w3;  d = w123 + 1048576; o = i - 262144; }
    else if (i < 1179648) { s = wh;  d = whB;            o = i - 393216; }
    else if (i < 2228224) { s = wd1; d = wd1B;           o = i - 1179648; }
    else                  { s = wd2; d = wd2B;           o = i - 2228224; ns = 512000; }
    bf16x4 v;
    if (o < ns) {
      float4 f = ((const float4*)s)[o];
      v[0] = (bf16_t)f.x; v[1] = (bf16_t)f.y; v[2] = (bf16_t)f.z; v[3] = (bf16_t)f.w;
    } else {
      v[0] = (bf16_t)0.0f; v[1] = (bf16_t)0.0f; v[2] = (bf16_t)0.0f; v[3] = (bf16_t)0.0f;
    }
    *(bf16x4*)(d + (size_t)o * 4) = v;
  }
}

__global__ void concat_bias3(const float* __restrict__ a, const float* __restrict__ b,
                             const float* __restrict__ c, float* __restrict__ dst) {
  int i = blockIdx.x * blockDim.x + threadIdx.x;
  if (i < 1024) dst[i] = a[i];
  else if (i < 2048) dst[i] = b[i - 1024];
  else if (i < 3072) dst[i] = c[i - 2048];
}

// ---------------- GEMM A: R2-exact (BK=32, 4-slot ring, counted vmcnt) ----------------
template<bool BDIAG, bool RELU, bool OUT_BF16>
__global__ __launch_bounds__(512, 2)
void gemm256(const bf16_t* __restrict__ A, int lda,
             const bf16_t* __restrict__ Bw, int ldb,
             const float* __restrict__ bias,
             void* __restrict__ Cout, int ldc,
             int K, int Nmask, int nbx)
{
  extern __shared__ char lds[];
  bf16_t* Ab = (bf16_t*)lds;
  bf16_t* Bb = (bf16_t*)(lds + 65536);

  const int t   = threadIdx.x;
  const int ln  = t & 63;
  const int w   = t >> 6;
  const int l15 = ln & 15, lhi = ln >> 4;
  const int wm  = w >> 2, wn = w & 3;

  const int nb = (int)gridDim.x;
  const int id = (int)blockIdx.x;
  const int id_sw = (id & 7) * (nb >> 3) + (id >> 3);
  const int bx = id_sw % nbx, by = id_sw / nbx;
  const int rowBase = by * 256;
  const int colBase = bx * 256;
  const int aCol0 = BDIAG ? (colBase >> 10) * 512 : 0;

  const int srow = (w << 4) + (ln >> 2);
  const int scol = (((ln & 3) ^ (ln >> 3)) & 3) << 3;

  const bf16_t* aS = A  + (size_t)(rowBase + srow) * lda + aCol0 + scol;
  const bf16_t* bS = Bw + (size_t)(colBase + srow) * ldb + scol;
  const size_t aI = (size_t)128 * lda;
  const size_t bI = (size_t)128 * ldb;
  bf16_t* daW = Ab + (w << 9);
  bf16_t* dbW = Bb + (w << 9);

  const int key  = (l15 >> 1) & 3;
  const int fcol = (lhi ^ key) << 3;
  const int aOff = (wm * 128 + l15) * 32 + fcol;
  const int bOff = (wn * 64  + l15) * 32 + fcol;

  const int nt = K >> 5;

  f32x4 acc[8][4] = {};

  #define STAGE(kt, s)                                                              \
    do {                                                                            \
      const bf16_t* a_ = aS + (size_t)(kt) * 32;                                    \
      const bf16_t* b_ = bS + (size_t)(kt) * 32;                                    \
      bf16_t* da_ = daW + (s) * 8192;                                               \
      bf16_t* db_ = dbW + (s) * 8192;                                               \
      __builtin_amdgcn_global_load_lds(AS1(a_),      AS3(da_),        16, 0, 0);    \
      __builtin_amdgcn_global_load_lds(AS1(a_ + aI), AS3(da_ + 4096), 16, 0, 0);    \
      __builtin_amdgcn_global_load_lds(AS1(b_),      AS3(db_),        16, 0, 0);    \
      __builtin_amdgcn_global_load_lds(AS1(b_ + bI), AS3(db_ + 4096), 16, 0, 0);    \
    } while (0)

  STAGE(0, 0); STAGE(1, 1); STAGE(2, 2);
  asm volatile("s_waitcnt vmcnt(8)" ::: "memory");
  __builtin_amdgcn_s_barrier();
  asm volatile("" ::: "memory");

  for (int j = 0; j < nt; ++j) {
    const int s = j & 3;
    const bf16_t* As_ = Ab + s * 8192 + aOff;
    const bf16_t* Bs_ = Bb + s * 8192 + bOff;

    bf16x8 af[8], bfr[4];
    #pragma unroll
    for (int mf = 0; mf < 8; ++mf) af[mf] = *(const bf16x8*)(As_ + mf * 512);
    #pragma unroll
    for (int nf = 0; nf < 4; ++nf) bfr[nf] = *(const bf16x8*)(Bs_ + nf * 512);

    if (j + 3 < nt) {
      STAGE(j + 3, ((j + 3) & 3));
      asm volatile("s_waitcnt vmcnt(8)" ::: "memory");
    } else if (j + 2 < nt) {
      asm volatile("s_waitcnt vmcnt(4)" ::: "memory");
    } else if (j + 1 < nt) {
      asm volatile("s_waitcnt vmcnt(0)" ::: "memory");
    }
    asm volatile("s_waitcnt lgkmcnt(0)" ::: "memory");
    __builtin_amdgcn_s_barrier();
    asm volatile("" ::: "memory");

    __builtin_amdgcn_s_setprio(1);
    #pragma unroll
    for (int mf = 0; mf < 8; ++mf)
      #pragma unroll
      for (int nf = 0; nf < 4; ++nf)
        acc[mf][nf] = __builtin_amdgcn_mfma_f32_16x16x32_bf16(af[mf], bfr[nf], acc[mf][nf], 0, 0, 0);
    __builtin_amdgcn_s_setprio(0);
  }
  #undef STAGE

  #pragma unroll
  for (int mf = 0; mf < 8; ++mf) {
    const int row = rowBase + wm * 128 + mf * 16 + lhi * 4;
    #pragma unroll
    for (int nf = 0; nf < 4; ++nf) {
      const int col = colBase + wn * 64 + nf * 16 + l15;
      const float bv = (col < Nmask) ? bias[col] : 0.0f;
      #pragma unroll
      for (int i = 0; i < 4; ++i) {
        float v = acc[mf][nf][i] + bv;
        if (RELU) v = fmaxf(v, 0.0f);
        if (OUT_BF16) {
          ((bf16_t*)Cout)[(size_t)(row + i) * ldc + col] = (bf16_t)v;
        } else {
          if (col < Nmask) ((float*)Cout)[(size_t)(row + i) * ldc + col] = v;
        }
      }
    }
  }
}

// ---------------- GEMM B: BK=64, 2-slot, single-barrier-per-tile (G4 A/B test) --------
// LDS: A slots [0,64K) 2x32KB, B slots [64K,128K). Rows are 128 B (64 bf16);
// swizzle granule(16B) ^= row&7 (guide G4 recipe). Stage: 8 loads/thread/tile.
// Iter: STAGE(j+1, s^1); reads(ks0); MFMA(ks0); reads(ks1); MFMA(ks1);
//       vmcnt(0)+lgkm(0)+barrier.  WAR: slot s^1 readers drained at bar(j-1).
//       RAW: STAGE(j) drained at bar(j-1). Drain covered by ~2500-cyc span.
template<bool RELU, bool OUT_BF16>
__global__ __launch_bounds__(512, 2)
void gemm256k64(const bf16_t* __restrict__ A, int lda,
                const bf16_t* __restrict__ Bw, int ldb,
                const float* __restrict__ bias,
                void* __restrict__ Cout, int ldc,
                int K, int Nmask, int nbx)
{
  extern __shared__ char lds[];

  const int t   = threadIdx.x;
  const int ln  = t & 63;
  const int w   = t >> 6;
  const int l15 = ln & 15, lhi = ln >> 4;
  const int wm  = w >> 2, wn = w & 3;

  const int nb = (int)gridDim.x;
  const int id = (int)blockIdx.x;
  const int id_sw = (id & 7) * (nb >> 3) + (id >> 3);
  const int bx = id_sw % nbx, by = id_sw / nbx;
  const int rowBase = by * 256;
  const int colBase = bx * 256;

  // staging: thread t, sub i in 0..3 -> LDS byte i*8192 + t*16 within slot;
  // row = i*64 + (t>>3); stored granule = t&7; source granule = (t&7)^((t>>3)&7)
  const int srow = t >> 3;
  const int scol = (((t & 7) ^ (t >> 3)) & 7) << 3;
  const bf16_t* aS = A  + (size_t)(rowBase + srow) * lda + scol;
  const bf16_t* bS = Bw + (size_t)(colBase + srow) * ldb + scol;
  const size_t aI = (size_t)64 * lda;
  const size_t bI = (size_t)64 * ldb;
  char* daT = lds + t * 16;            // + slot*32768 + i*8192
  char* dbT = lds + 65536 + t * 16;

  // frag read byte offsets within a slot: row*128 + ((ks*4+lhi)^(l15&7))*16
  const int rkey = l15 & 7;
  const int g0 = ((0 * 4 + lhi) ^ rkey) << 4;   // ks=0
  const int g1 = ((1 * 4 + lhi) ^ rkey) << 4;   // ks=1
  const int aRowB = (wm * 128 + l15) * 128;     // + mf*2048 (16 rows)
  const int bRowB = (wn * 64  + l15) * 128;     // + nf*2048

  const int nt = K >> 6;

  f32x4 acc[8][4] = {};

  #define STG64(kt, s)                                                              \
    do {                                                                            \
      const bf16_t* a_ = aS + (size_t)(kt) * 64;                                    \
      const bf16_t* b_ = bS + (size_t)(kt) * 64;                                    \
      char* da_ = daT + (s) * 32768;                                                \
      char* db_ = dbT + (s) * 32768;                                                \
      _Pragma("unroll")                                                             \
      for (int i_ = 0; i_ < 4; ++i_) {                                              \
        __builtin_amdgcn_global_load_lds(AS1(a_ + i_ * aI), AS3(da_ + i_ * 8192), 16, 0, 0); \
        __builtin_amdgcn_global_load_lds(AS1(b_ + i_ * bI), AS3(db_ + i_ * 8192), 16, 0, 0); \
      }                                                                             \
    } while (0)

  #define RD64(s, G, AF, BF)                                                        \
    do {                                                                            \
      const char* pa_ = lds + (s) * 32768 + aRowB + (G);                            \
      const char* pb_ = lds + 65536 + (s) * 32768 + bRowB + (G);                    \
      _Pragma("unroll")                                                             \
      for (int mf_ = 0; mf_ < 8; ++mf_) AF[mf_] = *(const bf16x8*)(pa_ + mf_ * 2048);\
      _Pragma("unroll")                                                             \
      for (int nf_ = 0; nf_ < 4; ++nf_) BF[nf_] = *(const bf16x8*)(pb_ + nf_ * 2048);\
    } while (0)

  #define MM64(AF, BF)                                                              \
    do {                                                                            \
      __builtin_amdgcn_s_setprio(1);                                                \
      _Pragma("unroll")                                                             \
      for (int mf_ = 0; mf_ < 8; ++mf_)                                             \
        _Pragma("unroll")                                                           \
        for (int nf_ = 0; nf_ < 4; ++nf_)                                           \
          acc[mf_][nf_] = __builtin_amdgcn_mfma_f32_16x16x32_bf16(                  \
              AF[mf_], BF[nf_], acc[mf_][nf_], 0, 0, 0);                            \
      __builtin_amdgcn_s_setprio(0);                                                \
    } while (0)

  // prologue
  STG64(0, 0);
  asm volatile("s_waitcnt vmcnt(0)" ::: "memory");
  __builtin_amdgcn_s_barrier();
  asm volatile("" ::: "memory");

  for (int j = 0; j < nt; ++j) {
    const int s = j & 1;
    if (j + 1 < nt) STG64(j + 1, s ^ 1);

    bf16x8 af[8], bfr[4];
    RD64(s, g0, af, bfr);
    MM64(af, bfr);            // compiler counted-lgkm: starts after first frags
    RD64(s, g1, af, bfr);     // issues during ks0 MFMA window
    MM64(af, bfr);

    if (j + 1 < nt) {
      asm volatile("s_waitcnt vmcnt(0)" ::: "memory");   // tile j+1 arrived (span-covered)
      asm volatile("s_waitcnt lgkmcnt(0)" ::: "memory"); // WAR: slot-s reads done
      __builtin_amdgcn_s_barrier();
      asm volatile("" ::: "memory");
    }
  }
  #undef STG64
  #undef RD64
  #undef MM64

  #pragma unroll
  for (int mf = 0; mf < 8; ++mf) {
    const int row = rowBase + wm * 128 + mf * 16 + lhi * 4;
    #pragma unroll
    for (int nf = 0; nf < 4; ++nf) {
      const int col = colBase + wn * 64 + nf * 16 + l15;
      const float bv = (col < Nmask) ? bias[col] : 0.0f;
      #pragma unroll
      for (int i = 0; i < 4; ++i) {
        float v = acc[mf][nf][i] + bv;
        if (RELU) v = fmaxf(v, 0.0f);
        if (OUT_BF16) {
          ((bf16_t*)Cout)[(size_t)(row + i) * ldc + col] = (bf16_t)v;
        } else {
          if (col < Nmask) ((float*)Cout)[(size_t)(row + i) * ldc + col] = v;
        }
      }
    }
  }
}

// ---------------- alphas -> softmax -> context (one block per row) ----------------
__global__ __launch_bounds__(256)
void attn_ctx(const bf16_t* __restrict__ P, bf16_t* __restrict__ ds) {
  __shared__ float red[3][4];
  __shared__ float wsh[3];
  const int r = blockIdx.x;
  const int t = threadIdx.x;
  const bf16_t* Prow = P + (size_t)r * 3072;
  bf16_t* dsrow = ds + (size_t)r * 2048;

  const int j = t * 4;
  bf16x4 lv = *(const bf16x4*)(dsrow + 1024 + j);
  float lhv[4], pv[3][4];
  float s[3] = {0.f, 0.f, 0.f};
  #pragma unroll
  for (int q = 0; q < 4; q++) lhv[q] = (float)lv[q];
  #pragma unroll
  for (int e = 0; e < 3; e++) {
    bf16x4 p = *(const bf16x4*)(Prow + e * 1024 + j);
    #pragma unroll
    for (int q = 0; q < 4; q++) {
      pv[e][q] = (float)p[q];
      s[e] += lhv[q] * pv[e][q];
    }
  }
  #pragma unroll
  for (int off = 32; off > 0; off >>= 1) {
    #pragma unroll
    for (int e = 0; e < 3; e++) s[e] += __shfl_down(s[e], off, 64);
  }
  const int w = t >> 6, l = t & 63;
  if (l == 0) {
    #pragma unroll
    for (int e = 0; e < 3; e++) red[e][w] = s[e];
  }
  __syncthreads();
  if (t == 0) {
    float a0 = red[0][0] + red[0][1] + red[0][2] + red[0][3];
    float a1 = red[1][0] + red[1][1] + red[1][2] + red[1][3];
    float a2 = red[2][0] + red[2][1] + red[2][2] + red[2][3];
    float mx = fmaxf(a0, fmaxf(a1, a2));
    float e0 = expf(a0 - mx), e1 = expf(a1 - mx), e2 = expf(a2 - mx);
    float inv = 1.0f / (e0 + e1 + e2);
    wsh[0] = e0 * inv; wsh[1] = e1 * inv; wsh[2] = e2 * inv;
  }
  __syncthreads();
  const float w0 = wsh[0], w1 = wsh[1], w2 = wsh[2];
  bf16x4 o;
  #pragma unroll
  for (int q = 0; q < 4; q++)
    o[q] = (bf16_t)(w0 * pv[0][q] + w1 * pv[1][q] + w2 * pv[2][q]);
  *(bf16x4*)(dsrow + j) = o;
}

// ---------------- launch ----------------
extern "C" void kernel_launch(void* const* d_in, const int* in_sizes, int n_in,
                              void* d_out, int out_size, void* d_ws, size_t ws_size,
                              hipStream_t stream) {
  (void)in_sizes; (void)n_in; (void)out_size; (void)ws_size;

  const float* tube = (const float*)d_in[0];
  const float* w1W  = (const float*)d_in[1];
  const float* w1b  = (const float*)d_in[2];
  const float* w2W  = (const float*)d_in[3];
  const float* w2b  = (const float*)d_in[4];
  const float* w3W  = (const float*)d_in[5];
  const float* w3b  = (const float*)d_in[6];
  const float* whW  = (const float*)d_in[7];
  const float* whb  = (const float*)d_in[8];
  const float* wd1W = (const float*)d_in[9];
  const float* wd1b = (const float*)d_in[10];
  const float* wd2W = (const float*)d_in[11];
  const float* wd2b = (const float*)d_in[12];

  char* ws = (char*)d_ws;
  bf16_t* P       = (bf16_t*)(ws + 0);            // 16384x3072
  bf16_t* ds      = (bf16_t*)(ws + 100663296);    // 16384x2048
  bf16_t* wd1B    = (bf16_t*)(ws + 167772160);    // 2048x2048
  bf16_t* wd2B    = (bf16_t*)(ws + 176160768);    // 1024x2048 (rows 1000.. zero)
  bf16_t* whB     = (bf16_t*)(ws + 180355072);    // 1024x3072
  bf16_t* w123B   = (bf16_t*)(ws + 186646528);    // 3072x512
  bf16_t* tubeB   = (bf16_t*)(ws + 189792256);    // 16384x1536
  bf16_t* out1    = (bf16_t*)(ws + 180355072);    // 16384x2048, aliases whB..tubeB
  float*  bias123 = (float*)(ws + 247463936);     // 3072 f32

  hipFuncSetAttribute((const void*)(gemm256<true,  true,  true >),
                      hipFuncAttributeMaxDynamicSharedMemorySize, 131072);
  hipFuncSetAttribute((const void*)(gemm256<false, true,  true >),
                      hipFuncAttributeMaxDynamicSharedMemorySize, 131072);
  hipFuncSetAttribute((const void*)(gemm256<false, false, false>),
                      hipFuncAttributeMaxDynamicSharedMemorySize, 131072);
  hipFuncSetAttribute((const void*)(gemm256k64<true, true>),
                      hipFuncAttributeMaxDynamicSharedMemorySize, 131072);

  hipLaunchKernelGGL(cvt_f32_bf16_v4, dim3(2048), dim3(256), 0, stream,
                     tube, tubeB, 6291456, 6291456);
  hipLaunchKernelGGL(cvt_weights, dim3(2048), dim3(256), 0, stream,
                     w1W, w2W, w3W, whW, wd1W, wd2W, w123B, whB, wd1B, wd2B);
  hipLaunchKernelGGL(concat_bias3, dim3(12), dim3(256), 0, stream, w1b, w2b, w3b, bias123);

  // G1: P = relu(block-diag expert GEMM), N=3072, K=512  [R2-exact]
  hipLaunchKernelGGL((gemm256<true, true, true>), dim3(12 * 64), dim3(512), 131072, stream,
                     tubeB, 1536, w123B, 512, bias123, (void*)P, 3072, 512, 3072, 12);
  // G2: ds[:,1024:2048] = relu(P @ wh^T + b), N=1024, K=3072  [R2-exact]
  hipLaunchKernelGGL((gemm256<false, true, true>), dim3(4 * 64), dim3(512), 131072, stream,
                     P, 3072, whB, 3072, whb, (void*)(ds + 1024), 2048, 3072, 1024, 4);
  // attn
  hipLaunchKernelGGL(attn_ctx, dim3(16384), dim3(256), 0, stream, P, ds);
  // G4: out1 = relu(ds @ wd1^T + b), N=2048, K=2048  [NEW BK=64 single-barrier]
  hipLaunchKernelGGL((gemm256k64<true, true>), dim3(8 * 64), dim3(512), 131072, stream,
                     ds, 2048, wd1B, 2048, wd1b, (void*)out1, 2048, 2048, 2048, 8);
  // G5: out = out1 @ wd2^T + b (fp32, N masked to 1000), K=2048  [R2-exact]
  hipLaunchKernelGGL((gemm256<false, false, false>), dim3(4 * 64), dim3(512), 131072, stream,
                     out1, 2048, wd2B, 2048, wd2b, d_out, 1000, 2048, 1000, 4);
}

// Round 17
// 410.149 us; speedup vs baseline: 5.6560x; 1.0098x over previous
//
#include <hip/hip_runtime.h>
#include <hip/hip_bf16.h>

// ClassAtt fused pipeline. R17 = R16 GEMMs (plateau-characterized: R2-exact
// for G1/G2/G5, BK=64 single-barrier for G4, both ~45% MfmaUtil) with the
// non-GEMM remainder harvested:
//  - attn_ctx: one WAVE per row (no LDS, no __syncthreads, no serial lane),
//    bf16x8 loads, shfl_xor butterfly all-reduce.
//  - all conversions (tube + 6 weights + bias concat) in ONE launch.

typedef __bf16 bf16_t;
typedef __bf16 bf16x4 __attribute__((ext_vector_type(4)));
typedef __bf16 bf16x8 __attribute__((ext_vector_type(8)));
typedef float  f32x4  __attribute__((ext_vector_type(4)));

#define AS1(p) (const __attribute__((address_space(1))) void*)(p)
#define AS3(p) (__attribute__((address_space(3))) void*)(p)

// ---------------- ALL conversions in one launch ----------------
// v4 ranges: tube [0,6291456) w1 [..,6422528) w2 [..,6553600) w3 [..,6684672)
//            wh [..,7471104) wd1 [..,8519680) wd2 [..,9043968, ns=512000)
//            bias concat (f32 copy) [9043968, 9044736)
__global__ void cvt_all(const float* __restrict__ tube,
                        const float* __restrict__ w1, const float* __restrict__ w2,
                        const float* __restrict__ w3, const float* __restrict__ wh,
                        const float* __restrict__ wd1, const float* __restrict__ wd2,
                        const float* __restrict__ w1b, const float* __restrict__ w2b,
                        const float* __restrict__ w3b,
                        bf16_t* __restrict__ tubeB, bf16_t* __restrict__ w123,
                        bf16_t* __restrict__ whB, bf16_t* __restrict__ wd1B,
                        bf16_t* __restrict__ wd2B, float* __restrict__ bias123) {
  const int stride = gridDim.x * blockDim.x;
  for (int i = blockIdx.x * blockDim.x + threadIdx.x; i < 9044736; i += stride) {
    if (i >= 9043968) {                       // bias concat, f32 float4 copy
      int o = i - 9043968;
      const float* sb; int oo;
      if (o < 256)      { sb = w1b; oo = o; }
      else if (o < 512) { sb = w2b; oo = o - 256; }
      else              { sb = w3b; oo = o - 512; }
      ((float4*)bias123)[o] = ((const float4*)sb)[oo];
      continue;
    }
    const float* s; bf16_t* d; int o; int ns = 1 << 30;
    if (i < 6291456)      { s = tube; d = tubeB;          o = i; }
    else if (i < 6422528) { s = w1;  d = w123;            o = i - 6291456; }
    else if (i < 6553600) { s = w2;  d = w123 + 524288;   o = i - 6422528; }
    else if (i < 6684672) { s = w3;  d = w123 + 1048576;  o = i - 6553600; }
    else if (i < 7471104) { s = wh;  d = whB;             o = i - 6684672; }
    else if (i < 8519680) { s = wd1; d = wd1B;            o = i - 7471104; }
    else                  { s = wd2; d = wd2B;            o = i - 8519680; ns = 512000; }
    bf16x4 v;
    if (o < ns) {
      float4 f = ((const float4*)s)[o];
      v[0] = (bf16_t)f.x; v[1] = (bf16_t)f.y; v[2] = (bf16_t)f.z; v[3] = (bf16_t)f.w;
    } else {
      v[0] = (bf16_t)0.0f; v[1] = (bf16_t)0.0f; v[2] = (bf16_t)0.0f; v[3] = (bf16_t)0.0f;
    }
    *(bf16x4*)(d + (size_t)o * 4) = v;
  }
}

// ---------------- GEMM A: R2-exact (BK=32, 4-slot ring, counted vmcnt) ----------------
template<bool BDIAG, bool RELU, bool OUT_BF16>
__global__ __launch_bounds__(512, 2)
void gemm256(const bf16_t* __restrict__ A, int lda,
             const bf16_t* __restrict__ Bw, int ldb,
             const float* __restrict__ bias,
             void* __restrict__ Cout, int ldc,
             int K, int Nmask, int nbx)
{
  extern __shared__ char lds[];
  bf16_t* Ab = (bf16_t*)lds;
  bf16_t* Bb = (bf16_t*)(lds + 65536);

  const int t   = threadIdx.x;
  const int ln  = t & 63;
  const int w   = t >> 6;
  const int l15 = ln & 15, lhi = ln >> 4;
  const int wm  = w >> 2, wn = w & 3;

  const int nb = (int)gridDim.x;
  const int id = (int)blockIdx.x;
  const int id_sw = (id & 7) * (nb >> 3) + (id >> 3);
  const int bx = id_sw % nbx, by = id_sw / nbx;
  const int rowBase = by * 256;
  const int colBase = bx * 256;
  const int aCol0 = BDIAG ? (colBase >> 10) * 512 : 0;

  const int srow = (w << 4) + (ln >> 2);
  const int scol = (((ln & 3) ^ (ln >> 3)) & 3) << 3;

  const bf16_t* aS = A  + (size_t)(rowBase + srow) * lda + aCol0 + scol;
  const bf16_t* bS = Bw + (size_t)(colBase + srow) * ldb + scol;
  const size_t aI = (size_t)128 * lda;
  const size_t bI = (size_t)128 * ldb;
  bf16_t* daW = Ab + (w << 9);
  bf16_t* dbW = Bb + (w << 9);

  const int key  = (l15 >> 1) & 3;
  const int fcol = (lhi ^ key) << 3;
  const int aOff = (wm * 128 + l15) * 32 + fcol;
  const int bOff = (wn * 64  + l15) * 32 + fcol;

  const int nt = K >> 5;

  f32x4 acc[8][4] = {};

  #define STAGE(kt, s)                                                              \
    do {                                                                            \
      const bf16_t* a_ = aS + (size_t)(kt) * 32;                                    \
      const bf16_t* b_ = bS + (size_t)(kt) * 32;                                    \
      bf16_t* da_ = daW + (s) * 8192;                                               \
      bf16_t* db_ = dbW + (s) * 8192;                                               \
      __builtin_amdgcn_global_load_lds(AS1(a_),      AS3(da_),        16, 0, 0);    \
      __builtin_amdgcn_global_load_lds(AS1(a_ + aI), AS3(da_ + 4096), 16, 0, 0);    \
      __builtin_amdgcn_global_load_lds(AS1(b_),      AS3(db_),        16, 0, 0);    \
      __builtin_amdgcn_global_load_lds(AS1(b_ + bI), AS3(db_ + 4096), 16, 0, 0);    \
    } while (0)

  STAGE(0, 0); STAGE(1, 1); STAGE(2, 2);
  asm volatile("s_waitcnt vmcnt(8)" ::: "memory");
  __builtin_amdgcn_s_barrier();
  asm volatile("" ::: "memory");

  for (int j = 0; j < nt; ++j) {
    const int s = j & 3;
    const bf16_t* As_ = Ab + s * 8192 + aOff;
    const bf16_t* Bs_ = Bb + s * 8192 + bOff;

    bf16x8 af[8], bfr[4];
    #pragma unroll
    for (int mf = 0; mf < 8; ++mf) af[mf] = *(const bf16x8*)(As_ + mf * 512);
    #pragma unroll
    for (int nf = 0; nf < 4; ++nf) bfr[nf] = *(const bf16x8*)(Bs_ + nf * 512);

    if (j + 3 < nt) {
      STAGE(j + 3, ((j + 3) & 3));
      asm volatile("s_waitcnt vmcnt(8)" ::: "memory");
    } else if (j + 2 < nt) {
      asm volatile("s_waitcnt vmcnt(4)" ::: "memory");
    } else if (j + 1 < nt) {
      asm volatile("s_waitcnt vmcnt(0)" ::: "memory");
    }
    asm volatile("s_waitcnt lgkmcnt(0)" ::: "memory");
    __builtin_amdgcn_s_barrier();
    asm volatile("" ::: "memory");

    __builtin_amdgcn_s_setprio(1);
    #pragma unroll
    for (int mf = 0; mf < 8; ++mf)
      #pragma unroll
      for (int nf = 0; nf < 4; ++nf)
        acc[mf][nf] = __builtin_amdgcn_mfma_f32_16x16x32_bf16(af[mf], bfr[nf], acc[mf][nf], 0, 0, 0);
    __builtin_amdgcn_s_setprio(0);
  }
  #undef STAGE

  #pragma unroll
  for (int mf = 0; mf < 8; ++mf) {
    const int row = rowBase + wm * 128 + mf * 16 + lhi * 4;
    #pragma unroll
    for (int nf = 0; nf < 4; ++nf) {
      const int col = colBase + wn * 64 + nf * 16 + l15;
      const float bv = (col < Nmask) ? bias[col] : 0.0f;
      #pragma unroll
      for (int i = 0; i < 4; ++i) {
        float v = acc[mf][nf][i] + bv;
        if (RELU) v = fmaxf(v, 0.0f);
        if (OUT_BF16) {
          ((bf16_t*)Cout)[(size_t)(row + i) * ldc + col] = (bf16_t)v;
        } else {
          if (col < Nmask) ((float*)Cout)[(size_t)(row + i) * ldc + col] = v;
        }
      }
    }
  }
}

// ---------------- GEMM B: BK=64, 2-slot, single-barrier-per-tile (G4) --------
template<bool RELU, bool OUT_BF16>
__global__ __launch_bounds__(512, 2)
void gemm256k64(const bf16_t* __restrict__ A, int lda,
                const bf16_t* __restrict__ Bw, int ldb,
                const float* __restrict__ bias,
                void* __restrict__ Cout, int ldc,
                int K, int Nmask, int nbx)
{
  extern __shared__ char lds[];

  const int t   = threadIdx.x;
  const int ln  = t & 63;
  const int w   = t >> 6;
  const int l15 = ln & 15, lhi = ln >> 4;
  const int wm  = w >> 2, wn = w & 3;

  const int nb = (int)gridDim.x;
  const int id = (int)blockIdx.x;
  const int id_sw = (id & 7) * (nb >> 3) + (id >> 3);
  const int bx = id_sw % nbx, by = id_sw / nbx;
  const int rowBase = by * 256;
  const int colBase = bx * 256;

  const int srow = t >> 3;
  const int scol = (((t & 7) ^ (t >> 3)) & 7) << 3;
  const bf16_t* aS = A  + (size_t)(rowBase + srow) * lda + scol;
  const bf16_t* bS = Bw + (size_t)(colBase + srow) * ldb + scol;
  const size_t aI = (size_t)64 * lda;
  const size_t bI = (size_t)64 * ldb;
  char* daT = lds + t * 16;
  char* dbT = lds + 65536 + t * 16;

  const int rkey = l15 & 7;
  const int g0 = ((0 * 4 + lhi) ^ rkey) << 4;
  const int g1 = ((1 * 4 + lhi) ^ rkey) << 4;
  const int aRowB = (wm * 128 + l15) * 128;
  const int bRowB = (wn * 64  + l15) * 128;

  const int nt = K >> 6;

  f32x4 acc[8][4] = {};

  #define STG64(kt, s)                                                              \
    do {                                                                            \
      const bf16_t* a_ = aS + (size_t)(kt) * 64;                                    \
      const bf16_t* b_ = bS + (size_t)(kt) * 64;                                    \
      char* da_ = daT + (s) * 32768;                                                \
      char* db_ = dbT + (s) * 32768;                                                \
      _Pragma("unroll")                                                             \
      for (int i_ = 0; i_ < 4; ++i_) {                                              \
        __builtin_amdgcn_global_load_lds(AS1(a_ + i_ * aI), AS3(da_ + i_ * 8192), 16, 0, 0); \
        __builtin_amdgcn_global_load_lds(AS1(b_ + i_ * bI), AS3(db_ + i_ * 8192), 16, 0, 0); \
      }                                                                             \
    } while (0)

  #define RD64(s, G, AF, BF)                                                        \
    do {                                                                            \
      const char* pa_ = lds + (s) * 32768 + aRowB + (G);                            \
      const char* pb_ = lds + 65536 + (s) * 32768 + bRowB + (G);                    \
      _Pragma("unroll")                                                             \
      for (int mf_ = 0; mf_ < 8; ++mf_) AF[mf_] = *(const bf16x8*)(pa_ + mf_ * 2048);\
      _Pragma("unroll")                                                             \
      for (int nf_ = 0; nf_ < 4; ++nf_) BF[nf_] = *(const bf16x8*)(pb_ + nf_ * 2048);\
    } while (0)

  #define MM64(AF, BF)                                                              \
    do {                                                                            \
      __builtin_amdgcn_s_setprio(1);                                                \
      _Pragma("unroll")                                                             \
      for (int mf_ = 0; mf_ < 8; ++mf_)                                             \
        _Pragma("unroll")                                                           \
        for (int nf_ = 0; nf_ < 4; ++nf_)                                           \
          acc[mf_][nf_] = __builtin_amdgcn_mfma_f32_16x16x32_bf16(                  \
              AF[mf_], BF[nf_], acc[mf_][nf_], 0, 0, 0);                            \
      __builtin_amdgcn_s_setprio(0);                                                \
    } while (0)

  STG64(0, 0);
  asm volatile("s_waitcnt vmcnt(0)" ::: "memory");
  __builtin_amdgcn_s_barrier();
  asm volatile("" ::: "memory");

  for (int j = 0; j < nt; ++j) {
    const int s = j & 1;
    if (j + 1 < nt) STG64(j + 1, s ^ 1);

    bf16x8 af[8], bfr[4];
    RD64(s, g0, af, bfr);
    MM64(af, bfr);
    RD64(s, g1, af, bfr);
    MM64(af, bfr);

    if (j + 1 < nt) {
      asm volatile("s_waitcnt vmcnt(0)" ::: "memory");
      asm volatile("s_waitcnt lgkmcnt(0)" ::: "memory");
      __builtin_amdgcn_s_barrier();
      asm volatile("" ::: "memory");
    }
  }
  #undef STG64
  #undef RD64
  #undef MM64

  #pragma unroll
  for (int mf = 0; mf < 8; ++mf) {
    const int row = rowBase + wm * 128 + mf * 16 + lhi * 4;
    #pragma unroll
    for (int nf = 0; nf < 4; ++nf) {
      const int col = colBase + wn * 64 + nf * 16 + l15;
      const float bv = (col < Nmask) ? bias[col] : 0.0f;
      #pragma unroll
      for (int i = 0; i < 4; ++i) {
        float v = acc[mf][nf][i] + bv;
        if (RELU) v = fmaxf(v, 0.0f);
        if (OUT_BF16) {
          ((bf16_t*)Cout)[(size_t)(row + i) * ldc + col] = (bf16_t)v;
        } else {
          if (col < Nmask) ((float*)Cout)[(size_t)(row + i) * ldc + col] = v;
        }
      }
    }
  }
}

// ---------------- alphas -> softmax -> context: ONE WAVE PER ROW ----------------
// 4 rows per 256-thread block; lane l owns 16 contiguous elems. No LDS, no
// __syncthreads, no serial lane: shfl_xor butterfly all-reduce, per-lane softmax.
__global__ __launch_bounds__(256)
void attn_ctx(const bf16_t* __restrict__ P, bf16_t* __restrict__ ds) {
  const int w = threadIdx.x >> 6;
  const int l = threadIdx.x & 63;
  const int r = (blockIdx.x << 2) + w;
  const bf16_t* Prow = P + (size_t)r * 3072;
  bf16_t* dsrow = ds + (size_t)r * 2048;
  const int j = l << 4;

  bf16x8 lv0 = *(const bf16x8*)(dsrow + 1024 + j);
  bf16x8 lv1 = *(const bf16x8*)(dsrow + 1024 + j + 8);
  float lhf[16];
  #pragma unroll
  for (int q = 0; q < 8; ++q) { lhf[q] = (float)lv0[q]; lhf[8 + q] = (float)lv1[q]; }

  float pv[3][16];
  float s[3] = {0.f, 0.f, 0.f};
  #pragma unroll
  for (int e = 0; e < 3; ++e) {
    bf16x8 p0 = *(const bf16x8*)(Prow + e * 1024 + j);
    bf16x8 p1 = *(const bf16x8*)(Prow + e * 1024 + j + 8);
    #pragma unroll
    for (int q = 0; q < 8; ++q) { pv[e][q] = (float)p0[q]; pv[e][8 + q] = (float)p1[q]; }
    #pragma unroll
    for (int q = 0; q < 16; ++q) s[e] += lhf[q] * pv[e][q];
  }
  #pragma unroll
  for (int off = 1; off < 64; off <<= 1) {
    #pragma unroll
    for (int e = 0; e < 3; ++e) s[e] += __shfl_xor(s[e], off, 64);
  }
  const float mx = fmaxf(s[0], fmaxf(s[1], s[2]));
  const float e0 = expf(s[0] - mx), e1 = expf(s[1] - mx), e2 = expf(s[2] - mx);
  const float inv = 1.0f / (e0 + e1 + e2);
  const float w0 = e0 * inv, w1 = e1 * inv, w2 = e2 * inv;

  bf16x8 o0, o1;
  #pragma unroll
  for (int q = 0; q < 8; ++q) {
    o0[q] = (bf16_t)(w0 * pv[0][q]     + w1 * pv[1][q]     + w2 * pv[2][q]);
    o1[q] = (bf16_t)(w0 * pv[0][8 + q] + w1 * pv[1][8 + q] + w2 * pv[2][8 + q]);
  }
  *(bf16x8*)(dsrow + j)     = o0;
  *(bf16x8*)(dsrow + j + 8) = o1;
}

// ---------------- launch ----------------
extern "C" void kernel_launch(void* const* d_in, const int* in_sizes, int n_in,
                              void* d_out, int out_size, void* d_ws, size_t ws_size,
                              hipStream_t stream) {
  (void)in_sizes; (void)n_in; (void)out_size; (void)ws_size;

  const float* tube = (const float*)d_in[0];
  const float* w1W  = (const float*)d_in[1];
  const float* w1b  = (const float*)d_in[2];
  const float* w2W  = (const float*)d_in[3];
  const float* w2b  = (const float*)d_in[4];
  const float* w3W  = (const float*)d_in[5];
  const float* w3b  = (const float*)d_in[6];
  const float* whW  = (const float*)d_in[7];
  const float* whb  = (const float*)d_in[8];
  const float* wd1W = (const float*)d_in[9];
  const float* wd1b = (const float*)d_in[10];
  const float* wd2W = (const float*)d_in[11];
  const float* wd2b = (const float*)d_in[12];

  char* ws = (char*)d_ws;
  bf16_t* P       = (bf16_t*)(ws + 0);            // 16384x3072
  bf16_t* ds      = (bf16_t*)(ws + 100663296);    // 16384x2048
  bf16_t* wd1B    = (bf16_t*)(ws + 167772160);    // 2048x2048
  bf16_t* wd2B    = (bf16_t*)(ws + 176160768);    // 1024x2048 (rows 1000.. zero)
  bf16_t* whB     = (bf16_t*)(ws + 180355072);    // 1024x3072
  bf16_t* w123B   = (bf16_t*)(ws + 186646528);    // 3072x512
  bf16_t* tubeB   = (bf16_t*)(ws + 189792256);    // 16384x1536
  bf16_t* out1    = (bf16_t*)(ws + 180355072);    // 16384x2048, aliases whB..tubeB
  float*  bias123 = (float*)(ws + 247463936);     // 3072 f32

  hipFuncSetAttribute((const void*)(gemm256<true,  true,  true >),
                      hipFuncAttributeMaxDynamicSharedMemorySize, 131072);
  hipFuncSetAttribute((const void*)(gemm256<false, true,  true >),
                      hipFuncAttributeMaxDynamicSharedMemorySize, 131072);
  hipFuncSetAttribute((const void*)(gemm256<false, false, false>),
                      hipFuncAttributeMaxDynamicSharedMemorySize, 131072);
  hipFuncSetAttribute((const void*)(gemm256k64<true, true>),
                      hipFuncAttributeMaxDynamicSharedMemorySize, 131072);

  // ALL conversions in one launch (tube + weights + bias concat)
  hipLaunchKernelGGL(cvt_all, dim3(4096), dim3(256), 0, stream,
                     tube, w1W, w2W, w3W, whW, wd1W, wd2W, w1b, w2b, w3b,
                     tubeB, w123B, whB, wd1B, wd2B, bias123);

  // G1: P = relu(block-diag expert GEMM), N=3072, K=512  [R2-exact]
  hipLaunchKernelGGL((gemm256<true, true, true>), dim3(12 * 64), dim3(512), 131072, stream,
                     tubeB, 1536, w123B, 512, bias123, (void*)P, 3072, 512, 3072, 12);
  // G2: ds[:,1024:2048] = relu(P @ wh^T + b), N=1024, K=3072  [R2-exact]
  hipLaunchKernelGGL((gemm256<false, true, true>), dim3(4 * 64), dim3(512), 131072, stream,
                     P, 3072, whB, 3072, whb, (void*)(ds + 1024), 2048, 3072, 1024, 4);
  // attn: wave-per-row softmax/context
  hipLaunchKernelGGL(attn_ctx, dim3(4096), dim3(256), 0, stream, P, ds);
  // G4: out1 = relu(ds @ wd1^T + b), N=2048, K=2048  [BK=64 single-barrier]
  hipLaunchKernelGGL((gemm256k64<true, true>), dim3(8 * 64), dim3(512), 131072, stream,
                     ds, 2048, wd1B, 2048, wd1b, (void*)out1, 2048, 2048, 2048, 8);
  // G5: out = out1 @ wd2^T + b (fp32, N masked to 1000), K=2048  [R2-exact]
  hipLaunchKernelGGL((gemm256<false, false, false>), dim3(4 * 64), dim3(512), 131072, stream,
                     out1, 2048, wd2B, 2048, wd2b, d_out, 1000, 2048, 1000, 4);
}